// Round 4
// baseline (68.574 us; speedup 1.0000x reference)
//
#include <hip/hip_runtime.h>

// ---- problem constants (match reference) ----
constexpr int B = 4, N = 4096;       // H*W = 64*64
constexpr int CCH = 13;              // 5 + NC
constexpr float LINE_W = 30.0f;
constexpr double EPS = 1e-05;
constexpr double DICE_W = 5.0;
constexpr int BCAP = 1024;           // per-(e,b,class) bucket capacity (expected ~256)

// ---- ws layout (float-indexed) ----
constexpr int EWP_OFF   = 0;                  // [11][256] elemwise per-wave partials
constexpr int PA_OFF    = 2816;               // [2048] pushall per-block partials
constexpr int BP_OFF    = 4864;               // [256][2] bucket per-block partials (pull, pushsame)
constexpr int CURS_OFF  = 5376;               // [64] int cursors (= exact class histograms)
constexpr int VCURS_OFF = 5440;               // [8] int valid-compaction cursors
constexpr int BUCK_OFF  = 5632;               // [64][BCAP] class buckets (NaN padded)
constexpr int VC_OFF    = BUCK_OFF + 64 * BCAP;   // [8][4096] compact valid values (NaN padded)
constexpr int WS_END    = VC_OFF + 8 * 4096;

__device__ inline float logsig(float x) {
    return fminf(x, 0.f) - log1pf(expf(-fabsf(x)));
}
__device__ inline float wave_reduce(float v) {
    #pragma unroll
    for (int off = 32; off > 0; off >>= 1) v += __shfl_down(v, off, 64);
    return v;
}
__device__ inline double wave_reduce_d(double v) {
    #pragma unroll
    for (int off = 32; off > 0; off >>= 1) v += __shfl_down(v, off, 64);
    return v;
}
__device__ inline float rdlane(float v, int k) {
    return __uint_as_float(__builtin_amdgcn_readlane(__float_as_uint(v), k));
}

// ---------------- Kernel A: elementwise terms + compaction/bucketing ----------
// grid = 64 blocks of 256 threads (1 pixel/thread)
__global__ __launch_bounds__(256) void elemwise_kernel(
        const float* __restrict__ outs, const float* __restrict__ gconf,
        const float* __restrict__ gox,  const float* __restrict__ goy,
        const int*   __restrict__ lidx, const int*   __restrict__ ign,
        const int*   __restrict__ fg,   const int*   __restrict__ lid,
        const float* __restrict__ gcls, float* __restrict__ ws) {
    const int b   = blockIdx.x >> 4;
    const int ln  = threadIdx.x & 63;
    const int wv  = threadIdx.x >> 6;
    const int n   = (blockIdx.x & 15) * 256 + threadIdx.x;
    const int pix = b * N + n;
    const int pslot = b * 64 + (blockIdx.x & 15) * 4 + wv;   // [0,256), wave-of-batch
    const float* ob = outs + (size_t)b * CCH * N;

    const float x  = ob[n];
    const float g  = gconf[pix];
    const float im = ign[pix] > 0 ? 1.f : 0.f;
    const bool  v  = fg[pix] > 0;
    const float ff = v ? 1.f : 0.f;

    // focal conf
    const float ls  = logsig(x);
    const float lns = logsig(-x);
    const float bce = -(g * ls + (1.f - g) * lns);
    const float p   = expf(-bce);
    const float conf = -(LINE_W * g * ls + (1.f - g) * lns);
    const float om  = 1.f - p;
    const float focal = om * om * conf * im;

    // dice partials
    const float ps = 1.f / (1.f + expf(-x));
    const float q = 1.f - ps, hh = 1.f - g;
    const float spg = ps * g * im,  spp = ps * ps * im,  sgg = g * g * im;
    const float s2pg = q * hh * im, s2pp = q * q * im,   s2gg = hh * hh * im;

    // offset MSE
    const float sox = 1.f / (1.f + expf(-ob[1 * N + n]));
    const float soy = 1.f / (1.f + expf(-ob[2 * N + n]));
    const float dx = sox - gox[pix], dy = soy - goy[pix];
    const float se = (dx * dx + dy * dy) * ff;

    // cls BCE (8 channels)
    float cl = 0.f;
    #pragma unroll
    for (int c = 0; c < 8; ++c) {
        const float z  = ob[(5 + c) * N + n];
        const float gc = gcls[((size_t)b * 8 + c) * N + n];
        cl += -(gc * logsig(z) + (1.f - gc) * logsig(-z));
    }
    cl *= ff;

    // ---- compaction & bucketing (wave-aggregated atomics) ----
    const float p3 = ob[3 * N + n], p4 = ob[4 * N + n];
    const int c0 = lidx[pix] & 7, c1 = lid[pix] & 7;
    int* curs  = (int*)(ws + CURS_OFF);
    int* vcurs = (int*)(ws + VCURS_OFF);

    const unsigned long long vm = __ballot(v);
    if (vm) {
        const int vcnt = __popcll(vm);
        const int vld  = __builtin_ctzll(vm);
        int vb0 = 0, vb1 = 0;
        if (ln == vld) { vb0 = atomicAdd(&vcurs[b], vcnt); vb1 = atomicAdd(&vcurs[4 + b], vcnt); }
        vb0 = __shfl(vb0, vld, 64);
        vb1 = __shfl(vb1, vld, 64);
        const int vr = __popcll(vm & ((1ull << ln) - 1ull));
        if (v) {
            ws[VC_OFF + b * 4096 + vb0 + vr]       = p3;
            ws[VC_OFF + (4 + b) * 4096 + vb1 + vr] = p4;
        }
    }
    #pragma unroll
    for (int c = 0; c < 8; ++c) {
        const unsigned long long m0 = __ballot(v && c0 == c);
        if (m0) {
            const int cnt = __popcll(m0), ld = __builtin_ctzll(m0);
            int base = 0;
            if (ln == ld) base = atomicAdd(&curs[b * 8 + c], cnt);
            base = __shfl(base, ld, 64);
            if (v && c0 == c) {
                const int slot = base + __popcll(m0 & ((1ull << ln) - 1ull));
                if (slot < BCAP) ws[BUCK_OFF + (b * 8 + c) * BCAP + slot] = p3;
            }
        }
        const unsigned long long m1 = __ballot(v && c1 == c);
        if (m1) {
            const int cnt = __popcll(m1), ld = __builtin_ctzll(m1);
            int base = 0;
            if (ln == ld) base = atomicAdd(&curs[32 + b * 8 + c], cnt);
            base = __shfl(base, ld, 64);
            if (v && c1 == c) {
                const int slot = base + __popcll(m1 & ((1ull << ln) - 1ull));
                if (slot < BCAP) ws[BUCK_OFF + (32 + b * 8 + c) * BCAP + slot] = p4;
            }
        }
    }

    // ---- per-wave partial writes (no f64 atomics) ----
    float vals[11] = {spg, spp, sgg, s2pg, s2pp, s2gg, im, focal, se, ff, cl};
    #pragma unroll
    for (int qq = 0; qq < 11; ++qq) {
        const float r = wave_reduce(vals[qq]);
        if (ln == 0) ws[EWP_OFF + qq * 256 + pslot] = r;
    }
}

// ---------------- Kernel B: pair sums over compacted arrays ----------------
// grid = 2048 (pushall: eb(8)|it(16)|js(16)) + 256 (buckets: bk(64)|js(4))
__global__ __launch_bounds__(256) void pair_kernel(float* __restrict__ ws) {
    const int bx  = blockIdx.x;
    const int tid = threadIdx.x;
    const int ln  = tid & 63;
    const int wv  = tid >> 6;
    const int* curs  = (const int*)(ws + CURS_OFF);
    const int* vcurs = (const int*)(ws + VCURS_OFF);

    float a0 = 0.f, a1 = 0.f, a2 = 0.f, a3 = 0.f;   // r0 = a0+a2, r1 = a1+a3

    if (bx < 2048) {
        // pushall over all valid pairs: hinge max(1-d, 0). NaN pads contribute 0.
        // NOTE: both even/odd accumulators feed r0 (a0, a2) — a1/a3 stay zero.
        const int eb = bx >> 8, it = (bx >> 4) & 15, js = bx & 15;
        const int m = min(vcurs[eb], 4096);
        if (it * 256 < m) {
            const float* arr = ws + VC_OFF + eb * 4096;
            const float pi = arr[it * 256 + tid];
            const int nch = (m + 63) >> 6;
            for (int cj = js; cj < nch; cj += 16) {
                const float jv = arr[cj * 64 + ln];
                #pragma unroll
                for (int k = 0; k < 64; k += 2) {
                    const float s0 = rdlane(jv, k);
                    const float s1 = rdlane(jv, k + 1);
                    a0 += fmaxf(1.f - fabsf(pi - s0), 0.f);
                    a2 += fmaxf(1.f - fabsf(pi - s1), 0.f);
                }
            }
        }
    } else {
        // per-class buckets: pull hinge max(d-0.5,0) and pushsame hinge max(1-d,0)
        const int bx2 = bx - 2048;            // [0,256)
        const int bk = bx2 >> 2, js = bx2 & 3;
        const int m = min(curs[bk], BCAP);
        const float* arr = ws + BUCK_OFF + bk * BCAP;
        const int nch = (m + 63) >> 6;
        for (int i0 = 0; i0 < m; i0 += 256) {
            const float pi = arr[i0 + tid];   // cap is a multiple of 256 -> in bounds
            for (int cj = js; cj < nch; cj += 4) {
                const float jv = arr[cj * 64 + ln];
                #pragma unroll
                for (int k = 0; k < 64; k += 2) {
                    const float d0 = fabsf(pi - rdlane(jv, k));
                    const float d1 = fabsf(pi - rdlane(jv, k + 1));
                    a0 += fmaxf(d0 - 0.5f, 0.f);   // pull
                    a2 += fmaxf(d1 - 0.5f, 0.f);
                    a1 += fmaxf(1.f - d0, 0.f);    // pushsame
                    a3 += fmaxf(1.f - d1, 0.f);
                }
            }
        }
    }

    // block reduce (s0 = pushall | pull ; s1 = - | pushsame)
    __shared__ float red[4][2];
    const float r0 = wave_reduce(a0 + a2);
    const float r1 = wave_reduce(a1 + a3);
    if (ln == 0) { red[wv][0] = r0; red[wv][1] = r1; }
    __syncthreads();
    if (tid == 0) {
        const float s0 = red[0][0] + red[1][0] + red[2][0] + red[3][0];
        const float s1 = red[0][1] + red[1][1] + red[2][1] + red[3][1];
        if (bx < 2048) {
            ws[PA_OFF + bx] = s0;
        } else {
            ws[BP_OFF + (bx - 2048) * 2 + 0] = s0;
            ws[BP_OFF + (bx - 2048) * 2 + 1] = s1;
        }
    }
}

// ---------------- Kernel C: finalize (1 block, 256 threads) ----------------
__global__ __launch_bounds__(256) void finalize_kernel(
        const float* __restrict__ ws, float* __restrict__ out) {
    const int tid = threadIdx.x, ln = tid & 63, wv = tid >> 6;
    __shared__ double ewb[4][7];   // per-batch dice partials + msum
    __shared__ double gsum[4];     // focal, se, fg, cls
    __shared__ double pa[8];
    __shared__ double bp[8][2];
    __shared__ double sred[4];

    // per-batch rows (wave wv <-> batch wv)
    #pragma unroll
    for (int q = 0; q < 7; ++q) {
        double v = (double)ws[EWP_OFF + q * 256 + tid];
        v = wave_reduce_d(v);
        if (ln == 0) ewb[wv][q] = v;
    }
    // global rows
    for (int q = 7; q < 11; ++q) {
        double v = (double)ws[EWP_OFF + q * 256 + tid];
        v = wave_reduce_d(v);
        if (ln == 0) sred[wv] = v;
        __syncthreads();
        if (tid == 0) gsum[q - 7] = sred[0] + sred[1] + sred[2] + sred[3];
        __syncthreads();
    }
    // pushall per eb
    for (int eb = 0; eb < 8; ++eb) {
        double v = (double)ws[PA_OFF + eb * 256 + tid];
        v = wave_reduce_d(v);
        if (ln == 0) sred[wv] = v;
        __syncthreads();
        if (tid == 0) pa[eb] = sred[0] + sred[1] + sred[2] + sred[3];
        __syncthreads();
    }
    // bucket partials: block bx2=tid, eb = tid>>5 (32 blocks per eb)
    #pragma unroll
    for (int q = 0; q < 2; ++q) {
        double v = (double)ws[BP_OFF + tid * 2 + q];
        #pragma unroll
        for (int off = 16; off > 0; off >>= 1) v += __shfl_down(v, off, 32);
        if ((tid & 31) == 0) bp[tid >> 5][q] = v;
    }
    __syncthreads();
    if (tid != 0) return;

    const int* curs = (const int*)(ws + CURS_OFF);

    double ign_sum = 0.0, dice = 0.0;
    for (int b = 0; b < B; ++b) {
        const double msum = ewb[b][6];
        ign_sum += msum;
        const double t = 1.0 - (ewb[b][0] + EPS) / (ewb[b][1] + ewb[b][2] + EPS)
                             - (ewb[b][3] + EPS) / (ewb[b][4] + ewb[b][5] + EPS);
        dice += (msum > 0.0) ? t : 0.0;
    }
    const double focal = gsum[0], se = gsum[1], ffs = gsum[2], clsum = gsum[3];
    const double conf_loss = focal / fmax(ign_sum, 1.0) + DICE_W * dice / B;
    const double off_loss  = se / fmax(2.0 * ffs, 1.0);

    double embv[2] = {0.0, 0.0};
    for (int e = 0; e < 2; ++e)
        for (int b = 0; b < B; ++b) {
            const int eb = e * 4 + b;
            double cs = 0.0, nv = 0.0;
            for (int c = 0; c < 8; ++c) {
                const double x = (double)curs[e * 32 + b * 8 + c];
                cs += x * x; nv += x;
            }
            const double cd = nv * nv - cs;
            const double pull = bp[eb][0] / fmax(cs, 1.0);
            const double pushsum = pa[eb] - bp[eb][1];
            const double push = (cd > 0.0) ? pushsum / fmax(cd, 1.0) : 0.0;
            embv[e] += pull + push;
        }

    const double cls_loss = clsum / fmax(8.0 * ffs, 1.0);
    const double total = conf_loss + 0.5 * off_loss
                       + embv[0] / B + embv[1] / B + cls_loss;
    out[0] = (float)total;
}

extern "C" void kernel_launch(void* const* d_in, const int* in_sizes, int n_in,
                              void* d_out, int out_size, void* d_ws, size_t ws_size,
                              hipStream_t stream) {
    const float* outs  = (const float*)d_in[0];
    const float* gconf = (const float*)d_in[1];
    const float* gox   = (const float*)d_in[2];
    const float* goy   = (const float*)d_in[3];
    const int*   lidx  = (const int*)d_in[4];
    const int*   ign   = (const int*)d_in[5];
    const int*   fg    = (const int*)d_in[6];
    const int*   lid   = (const int*)d_in[7];
    const float* gcls  = (const float*)d_in[8];
    float* ws = (float*)d_ws;

    // zero the cursors; fill buckets + compact arrays with qNaN (0xFF bytes)
    hipMemsetAsync((char*)d_ws + (size_t)CURS_OFF * 4, 0,
                   (size_t)(BUCK_OFF - CURS_OFF) * 4, stream);
    hipMemsetAsync((char*)d_ws + (size_t)BUCK_OFF * 4, 0xFF,
                   (size_t)(WS_END - BUCK_OFF) * 4, stream);

    elemwise_kernel<<<64, 256, 0, stream>>>(outs, gconf, gox, goy, lidx, ign, fg, lid, gcls, ws);
    pair_kernel<<<2048 + 256, 256, 0, stream>>>(ws);
    finalize_kernel<<<1, 256, 0, stream>>>(ws, (float*)d_out);
}

// Round 5
// 48.938 us; speedup vs baseline: 1.4013x; 1.4013x over previous
//
#include <hip/hip_runtime.h>

// ---- problem constants (match reference) ----
constexpr int B = 4, N = 4096;       // H*W = 64*64
constexpr int CCH = 13;              // 5 + NC
constexpr float LINE_W = 30.0f;
constexpr double EPS = 1e-05;
constexpr double DICE_W = 5.0;
constexpr int BCAP = 1024;           // per-(e,b,class) bucket capacity (expected ~256)

// ---- ws layout (float-indexed) ----
constexpr int EWP_OFF   = 0;                  // [11][256] elemwise per-wave partials
constexpr int PA_OFF    = 2816;               // [2048] pushall per-block partials
constexpr int BP_OFF    = 4864;               // [256][2] bucket per-block partials (pull, pushsame)
constexpr int CURS_OFF  = 5376;               // [64] int class histograms
constexpr int VCURS_OFF = 5440;               // [8] int valid counts
constexpr int BUCK_OFF  = 5632;               // [64][BCAP] class buckets (NaN padded to 256-mult)
constexpr int VC_OFF    = BUCK_OFF + 64 * BCAP;   // [8][4096] compact valid values (NaN padded)
constexpr int WS_END    = VC_OFF + 8 * 4096;

__device__ inline float logsig(float x) {
    return fminf(x, 0.f) - log1pf(expf(-fabsf(x)));
}
__device__ inline float wave_reduce(float v) {
    #pragma unroll
    for (int off = 32; off > 0; off >>= 1) v += __shfl_down(v, off, 64);
    return v;
}
__device__ inline double wave_reduce_d(double v) {
    #pragma unroll
    for (int off = 32; off > 0; off >>= 1) v += __shfl_down(v, off, 64);
    return v;
}
__device__ inline float rdlane(float v, int k) {
    return __uint_as_float(__builtin_amdgcn_readlane(__float_as_uint(v), k));
}

// ---------------- Kernel A: pure elementwise terms ----------------
// grid = 256 blocks of 64 threads (1 wave each, 1 pixel/thread)
__global__ __launch_bounds__(64) void elemwise_kernel(
        const float* __restrict__ outs, const float* __restrict__ gconf,
        const float* __restrict__ gox,  const float* __restrict__ goy,
        const int*   __restrict__ ign,  const int*   __restrict__ fg,
        const float* __restrict__ gcls, float* __restrict__ ws) {
    const int b    = blockIdx.x >> 6;
    const int tile = blockIdx.x & 63;
    const int tid  = threadIdx.x;
    const int n    = tile * 64 + tid;
    const int pix  = b * N + n;
    const int pslot = b * 64 + tile;          // [0,256)
    const float* ob = outs + (size_t)b * CCH * N;

    const float x  = ob[n];
    const float g  = gconf[pix];
    const float im = ign[pix] > 0 ? 1.f : 0.f;
    const float ff = fg[pix] > 0 ? 1.f : 0.f;

    // focal conf
    const float ls  = logsig(x);
    const float lns = logsig(-x);
    const float bce = -(g * ls + (1.f - g) * lns);
    const float p   = expf(-bce);
    const float conf = -(LINE_W * g * ls + (1.f - g) * lns);
    const float om  = 1.f - p;
    const float focal = om * om * conf * im;

    // dice partials
    const float ps = 1.f / (1.f + expf(-x));
    const float q = 1.f - ps, hh = 1.f - g;
    const float spg = ps * g * im,  spp = ps * ps * im,  sgg = g * g * im;
    const float s2pg = q * hh * im, s2pp = q * q * im,   s2gg = hh * hh * im;

    // offset MSE
    const float sox = 1.f / (1.f + expf(-ob[1 * N + n]));
    const float soy = 1.f / (1.f + expf(-ob[2 * N + n]));
    const float dx = sox - gox[pix], dy = soy - goy[pix];
    const float se = (dx * dx + dy * dy) * ff;

    // cls BCE (8 channels)
    float cl = 0.f;
    #pragma unroll
    for (int c = 0; c < 8; ++c) {
        const float z  = ob[(5 + c) * N + n];
        const float gc = gcls[((size_t)b * 8 + c) * N + n];
        cl += -(gc * logsig(z) + (1.f - gc) * logsig(-z));
    }
    cl *= ff;

    float vals[11] = {spg, spp, sgg, s2pg, s2pp, s2gg, im, focal, se, ff, cl};
    #pragma unroll
    for (int qq = 0; qq < 11; ++qq) {
        const float r = wave_reduce(vals[qq]);
        if (tid == 0) ws[EWP_OFF + qq * 256 + pslot] = r;
    }
}

// ---------------- Kernel A2: compaction/bucketing, LDS cursors ----------------
// grid = 8 blocks (one per eb), 1024 threads
__global__ __launch_bounds__(1024) void compact_kernel(
        const float* __restrict__ outs, const int* __restrict__ lidx,
        const int* __restrict__ lid,    const int* __restrict__ fg,
        float* __restrict__ ws) {
    const int eb = blockIdx.x;          // e*4 + b
    const int e = eb >> 2, b = eb & 3;
    const int tid = threadIdx.x, ln = tid & 63;
    const int* gsrc = e ? lid : lidx;
    const float* pch = outs + ((size_t)b * CCH + 3 + e) * N;

    __shared__ int lcurs[9];            // 8 class cursors + 1 valid cursor
    if (tid < 9) lcurs[tid] = 0;
    __syncthreads();

    for (int it = 0; it < 4; ++it) {
        const int n = it * 1024 + tid;
        const bool v = fg[b * N + n] > 0;
        const float val = pch[n];
        const int cc = gsrc[b * N + n] & 7;

        // valid compaction (wave-aggregated LDS atomic)
        const unsigned long long vm = __ballot(v);
        if (vm) {
            const int cnt = __popcll(vm), ld = __builtin_ctzll(vm);
            int base = 0;
            if (ln == ld) base = atomicAdd(&lcurs[8], cnt);
            base = __shfl(base, ld, 64);
            if (v) ws[VC_OFF + eb * 4096 + base + __popcll(vm & ((1ull << ln) - 1ull))] = val;
        }
        #pragma unroll
        for (int c = 0; c < 8; ++c) {
            const unsigned long long m = __ballot(v && cc == c);
            if (m) {
                const int cnt = __popcll(m), ld = __builtin_ctzll(m);
                int base = 0;
                if (ln == ld) base = atomicAdd(&lcurs[c], cnt);
                base = __shfl(base, ld, 64);
                if (v && cc == c) {
                    const int slot = base + __popcll(m & ((1ull << ln) - 1ull));
                    if (slot < BCAP) ws[BUCK_OFF + (e * 32 + b * 8 + c) * BCAP + slot] = val;
                }
            }
        }
    }
    __syncthreads();

    // publish cursors + NaN-pad tails up to next 256 multiple
    int* curs  = (int*)(ws + CURS_OFF);
    int* vcurs = (int*)(ws + VCURS_OFF);
    const float QNAN = __int_as_float(0x7FC00000);
    if (tid < 8) curs[e * 32 + b * 8 + tid] = min(lcurs[tid], BCAP);
    if (tid == 8) vcurs[eb] = lcurs[8];
    #pragma unroll
    for (int c = 0; c < 8; ++c) {
        const int mm = min(lcurs[c], BCAP);
        const int pad = ((mm + 255) & ~255) - mm;
        if (tid < pad) ws[BUCK_OFF + (e * 32 + b * 8 + c) * BCAP + mm + tid] = QNAN;
    }
    {
        const int mm = lcurs[8];        // <= 4096 by construction
        const int pad = ((mm + 255) & ~255) - mm;
        if (tid < pad && mm + tid < 4096) ws[VC_OFF + eb * 4096 + mm + tid] = QNAN;
    }
}

// ---------------- Kernel B: pair sums over compacted arrays ----------------
// grid = 2048 (pushall: eb(8)|it(16)|js(16)) + 256 (buckets: bk(64)|js(4))
__global__ __launch_bounds__(256) void pair_kernel(float* __restrict__ ws) {
    const int bx  = blockIdx.x;
    const int tid = threadIdx.x;
    const int ln  = tid & 63;
    const int wv  = tid >> 6;
    const int* curs  = (const int*)(ws + CURS_OFF);
    const int* vcurs = (const int*)(ws + VCURS_OFF);

    float a0 = 0.f, a1 = 0.f, a2 = 0.f, a3 = 0.f;   // r0 = a0+a2, r1 = a1+a3

    if (bx < 2048) {
        // pushall over all valid pairs: hinge max(1-d, 0). NaN pads contribute 0.
        const int eb = bx >> 8, it = (bx >> 4) & 15, js = bx & 15;
        const int m = min(vcurs[eb], 4096);
        if (it * 256 < m) {
            const float* arr = ws + VC_OFF + eb * 4096;
            const float pi = arr[it * 256 + tid];
            const int nch = (m + 63) >> 6;
            for (int cj = js; cj < nch; cj += 16) {
                const float jv = arr[cj * 64 + ln];
                #pragma unroll
                for (int k = 0; k < 64; k += 2) {
                    const float s0 = rdlane(jv, k);
                    const float s1 = rdlane(jv, k + 1);
                    a0 += fmaxf(1.f - fabsf(pi - s0), 0.f);
                    a2 += fmaxf(1.f - fabsf(pi - s1), 0.f);
                }
            }
        }
    } else {
        // per-class buckets: pull hinge max(d-0.5,0) and pushsame hinge max(1-d,0)
        const int bx2 = bx - 2048;            // [0,256)
        const int bk = bx2 >> 2, js = bx2 & 3;
        const int m = min(curs[bk], BCAP);
        const float* arr = ws + BUCK_OFF + bk * BCAP;
        const int nch = (m + 63) >> 6;
        for (int i0 = 0; i0 < m; i0 += 256) {
            const float pi = arr[i0 + tid];   // padded to 256-mult -> in bounds
            for (int cj = js; cj < nch; cj += 4) {
                const float jv = arr[cj * 64 + ln];
                #pragma unroll
                for (int k = 0; k < 64; k += 2) {
                    const float d0 = fabsf(pi - rdlane(jv, k));
                    const float d1 = fabsf(pi - rdlane(jv, k + 1));
                    a0 += fmaxf(d0 - 0.5f, 0.f);   // pull
                    a2 += fmaxf(d1 - 0.5f, 0.f);
                    a1 += fmaxf(1.f - d0, 0.f);    // pushsame
                    a3 += fmaxf(1.f - d1, 0.f);
                }
            }
        }
    }

    // block reduce (s0 = pushall | pull ; s1 = - | pushsame)
    __shared__ float red[4][2];
    const float r0 = wave_reduce(a0 + a2);
    const float r1 = wave_reduce(a1 + a3);
    if (ln == 0) { red[wv][0] = r0; red[wv][1] = r1; }
    __syncthreads();
    if (tid == 0) {
        const float s0 = red[0][0] + red[1][0] + red[2][0] + red[3][0];
        const float s1 = red[0][1] + red[1][1] + red[2][1] + red[3][1];
        if (bx < 2048) {
            ws[PA_OFF + bx] = s0;
        } else {
            ws[BP_OFF + (bx - 2048) * 2 + 0] = s0;
            ws[BP_OFF + (bx - 2048) * 2 + 1] = s1;
        }
    }
}

// ---------------- Kernel C: finalize (1 block, 256 threads) ----------------
__global__ __launch_bounds__(256) void finalize_kernel(
        const float* __restrict__ ws, float* __restrict__ out) {
    const int tid = threadIdx.x, ln = tid & 63, wv = tid >> 6;
    __shared__ double ewb[4][7];   // per-batch dice partials + msum
    __shared__ double gsum[4];     // focal, se, fg, cls
    __shared__ double pa[8];
    __shared__ double bp[8][2];
    __shared__ double sred[4];

    // per-batch rows (wave wv <-> batch wv)
    #pragma unroll
    for (int q = 0; q < 7; ++q) {
        double v = (double)ws[EWP_OFF + q * 256 + tid];
        v = wave_reduce_d(v);
        if (ln == 0) ewb[wv][q] = v;
    }
    // global rows
    for (int q = 7; q < 11; ++q) {
        double v = (double)ws[EWP_OFF + q * 256 + tid];
        v = wave_reduce_d(v);
        if (ln == 0) sred[wv] = v;
        __syncthreads();
        if (tid == 0) gsum[q - 7] = sred[0] + sred[1] + sred[2] + sred[3];
        __syncthreads();
    }
    // pushall per eb
    for (int eb = 0; eb < 8; ++eb) {
        double v = (double)ws[PA_OFF + eb * 256 + tid];
        v = wave_reduce_d(v);
        if (ln == 0) sred[wv] = v;
        __syncthreads();
        if (tid == 0) pa[eb] = sred[0] + sred[1] + sred[2] + sred[3];
        __syncthreads();
    }
    // bucket partials: block bx2=tid, eb = tid>>5 (32 blocks per eb)
    #pragma unroll
    for (int q = 0; q < 2; ++q) {
        double v = (double)ws[BP_OFF + tid * 2 + q];
        #pragma unroll
        for (int off = 16; off > 0; off >>= 1) v += __shfl_down(v, off, 32);
        if ((tid & 31) == 0) bp[tid >> 5][q] = v;
    }
    __syncthreads();
    if (tid != 0) return;

    const int* curs = (const int*)(ws + CURS_OFF);

    double ign_sum = 0.0, dice = 0.0;
    for (int b = 0; b < B; ++b) {
        const double msum = ewb[b][6];
        ign_sum += msum;
        const double t = 1.0 - (ewb[b][0] + EPS) / (ewb[b][1] + ewb[b][2] + EPS)
                             - (ewb[b][3] + EPS) / (ewb[b][4] + ewb[b][5] + EPS);
        dice += (msum > 0.0) ? t : 0.0;
    }
    const double focal = gsum[0], se = gsum[1], ffs = gsum[2], clsum = gsum[3];
    const double conf_loss = focal / fmax(ign_sum, 1.0) + DICE_W * dice / B;
    const double off_loss  = se / fmax(2.0 * ffs, 1.0);

    double embv[2] = {0.0, 0.0};
    for (int e = 0; e < 2; ++e)
        for (int b = 0; b < B; ++b) {
            const int eb = e * 4 + b;
            double cs = 0.0, nv = 0.0;
            for (int c = 0; c < 8; ++c) {
                const double x = (double)curs[e * 32 + b * 8 + c];
                cs += x * x; nv += x;
            }
            const double cd = nv * nv - cs;
            const double pull = bp[eb][0] / fmax(cs, 1.0);
            const double pushsum = pa[eb] - bp[eb][1];
            const double push = (cd > 0.0) ? pushsum / fmax(cd, 1.0) : 0.0;
            embv[e] += pull + push;
        }

    const double cls_loss = clsum / fmax(8.0 * ffs, 1.0);
    const double total = conf_loss + 0.5 * off_loss
                       + embv[0] / B + embv[1] / B + cls_loss;
    out[0] = (float)total;
}

extern "C" void kernel_launch(void* const* d_in, const int* in_sizes, int n_in,
                              void* d_out, int out_size, void* d_ws, size_t ws_size,
                              hipStream_t stream) {
    const float* outs  = (const float*)d_in[0];
    const float* gconf = (const float*)d_in[1];
    const float* gox   = (const float*)d_in[2];
    const float* goy   = (const float*)d_in[3];
    const int*   lidx  = (const int*)d_in[4];
    const int*   ign   = (const int*)d_in[5];
    const int*   fg    = (const int*)d_in[6];
    const int*   lid   = (const int*)d_in[7];
    const float* gcls  = (const float*)d_in[8];
    float* ws = (float*)d_ws;

    // no memsets needed: every ws location read downstream is written upstream
    compact_kernel<<<8, 1024, 0, stream>>>(outs, lidx, lid, fg, ws);
    elemwise_kernel<<<256, 64, 0, stream>>>(outs, gconf, gox, goy, ign, fg, gcls, ws);
    pair_kernel<<<2048 + 256, 256, 0, stream>>>(ws);
    finalize_kernel<<<1, 256, 0, stream>>>(ws, (float*)d_out);
}